// Round 1
// baseline (785.469 us; speedup 1.0000x reference)
//
#include <hip/hip_runtime.h>
#include <math.h>

#define LN2PI 1.83787706640934548356f

// ---------------------------------------------------------------------------
// 4x4 matmul V = W @ M   (row-major, m = r*4+c)
// ---------------------------------------------------------------------------
__device__ __forceinline__ void compute_V(const float* __restrict__ Wm,
                                          const float* __restrict__ Mm,
                                          float* V) {
    float w[16], m[16];
    #pragma unroll
    for (int k = 0; k < 16; ++k) { w[k] = Wm[k]; m[k] = Mm[k]; }
    #pragma unroll
    for (int r = 0; r < 4; ++r) {
        #pragma unroll
        for (int cc = 0; cc < 4; ++cc) {
            float s = w[r*4+0] * m[0*4+cc];
            s = fmaf(w[r*4+1], m[1*4+cc], s);
            s = fmaf(w[r*4+2], m[2*4+cc], s);
            s = fmaf(w[r*4+3], m[3*4+cc], s);
            V[r*4+cc] = s;
        }
    }
}

// ---------------------------------------------------------------------------
// stem: conv 5x5 stride 2 valid + bias + relu : (16,2,32,32) -> (16,32,14,14)
// ---------------------------------------------------------------------------
__global__ void k_stem(const float* __restrict__ x, const float* __restrict__ w,
                       const float* __restrict__ bias, float* __restrict__ fea) {
    int idx = blockIdx.x * blockDim.x + threadIdx.x;
    if (idx >= 16*32*14*14) return;
    int ox = idx % 14, oy = (idx/14) % 14, oc = (idx/196) % 32, b = idx/(196*32);
    float s = bias[oc];
    const float* xb = x + b*2*32*32;
    const float* wc = w + oc*2*25;
    #pragma unroll
    for (int ic = 0; ic < 2; ++ic)
        #pragma unroll
        for (int ky = 0; ky < 5; ++ky)
            #pragma unroll
            for (int kx = 0; kx < 5; ++kx)
                s = fmaf(xb[ic*1024 + (oy*2+ky)*32 + (ox*2+kx)],
                         wc[ic*25 + ky*5 + kx], s);
    fea[idx] = fmaxf(s, 0.f);
}

// ---------------------------------------------------------------------------
// primary caps: M[b,o,hw] (o<512) and a[b,oo,hw] = sigmoid(...) (o>=512)
// ---------------------------------------------------------------------------
__global__ void k_primary(const float* __restrict__ fea,
                          const float* __restrict__ pw, const float* __restrict__ pb,
                          const float* __restrict__ aw, const float* __restrict__ ab,
                          float* __restrict__ M, float* __restrict__ a) {
    int idx = blockIdx.x * blockDim.x + threadIdx.x;
    if (idx >= 16*544*196) return;
    int hw = idx % 196, o = (idx/196) % 544, b = idx/(196*544);
    const float* f = fea + b*32*196 + hw;
    if (o < 512) {
        float s = pb[o];
        #pragma unroll
        for (int c = 0; c < 32; ++c) s = fmaf(f[c*196], pw[o*32+c], s);
        M[(b*512+o)*196 + hw] = s;
    } else {
        int oo = o - 512;
        float s = ab[oo];
        #pragma unroll
        for (int c = 0; c < 32; ++c) s = fmaf(f[c*196], aw[oo*32+c], s);
        a[(b*32+oo)*196 + hw] = 1.f/(1.f + expf(-s));
    }
}

// ---------------------------------------------------------------------------
// patch extraction: aP[b,i,p], Mp[b,i,p,16]  (i = Bi*KK+kk, p = py*ow+px)
// ---------------------------------------------------------------------------
__global__ void k_patch(const float* __restrict__ a_in, const float* __restrict__ M_in,
                        float* __restrict__ aP, float* __restrict__ Mp,
                        int B, int K, int stride, int h, int w, int oh, int ow) {
    int P = oh*ow, KK = K*K, ni = B*KK;
    int idx = blockIdx.x * blockDim.x + threadIdx.x;
    if (idx >= 16*ni*P) return;
    int p = idx % P, i = (idx/P) % ni, b = idx/(P*ni);
    int Bi = i / KK, kk = i % KK, ki = kk / K, kj = kk % K;
    int py = p / ow, px = p % ow;
    int src = (py*stride + ki)*w + (px*stride + kj);
    int hw = h*w;
    aP[idx] = a_in[(b*B + Bi)*hw + src];
    const float* Ms = M_in + (size_t)((b*B + Bi)*16)*hw + src;
    float* Md = Mp + (size_t)idx*16;
    #pragma unroll
    for (int m = 0; m < 16; ++m) Md[m] = Ms[m*hw];
}

// ---------------------------------------------------------------------------
// EM stats: one wave per (b,j). coeff/miu/sigma reduce over ni, then a_out.
// Stores miu, 1/sigma, sum(log sigma), a_out; on final iter also layer outputs.
// ---------------------------------------------------------------------------
template<int NI, int NJ, int P, int C, int KK, int SHARE, int COORD>
__global__ __launch_bounds__(64) void k_stats(
    const float* __restrict__ aP, const float* __restrict__ Mp,
    const float* __restrict__ W, const float* __restrict__ R,
    const float* __restrict__ beta_a, const float* __restrict__ beta_u,
    float* __restrict__ miu, float* __restrict__ isig, float* __restrict__ lss,
    float* __restrict__ aout, float* __restrict__ a_fin, float* __restrict__ M_fin,
    int t, float lam, int final_flag)
{
    constexpr int NIT = (NI + 63) / 64;
    int j = blockIdx.x % NJ, bb = blockIdx.x / NJ;
    int c = j / P, p = j % P;
    int lane = threadIdx.x;

    float Vc[NIT][16];
    float wc[NIT];
    float accw = 0.f, accm[16];
    #pragma unroll
    for (int m = 0; m < 16; ++m) accm[m] = 0.f;

    #pragma unroll
    for (int it = 0; it < NIT; ++it) {
        int i = lane + it*64;
        wc[it] = 0.f;
        bool valid = (NI % 64 == 0) || (i < NI);
        if (valid) {
            float r = (t == 0) ? (1.f/NJ) : R[(size_t)(bb*NI + i)*NJ + j];
            float wgt = r * aP[(bb*NI + i)*P + p];
            const float* Wm = SHARE ? (W + ((i/KK)*C + c)*16)
                                    : (W + (i*C + c)*16);
            const float* Mm = Mp + (size_t)((bb*NI + i)*P + p)*16;
            float Vr[16];
            compute_V(Wm, Mm, Vr);
            if (COORD) {
                int kk = i % KK;
                Vr[0] += (float)(kk >> 2) * 0.25f;
                Vr[1] += (float)(kk & 3) * 0.25f;
            }
            wc[it] = wgt;
            accw += wgt;
            #pragma unroll
            for (int m = 0; m < 16; ++m) { Vc[it][m] = Vr[m]; accm[m] = fmaf(wgt, Vr[m], accm[m]); }
        } else {
            #pragma unroll
            for (int m = 0; m < 16; ++m) Vc[it][m] = 0.f;
        }
    }

    // wave butterfly reduce coeff + miu sums
    for (int off = 1; off < 64; off <<= 1) {
        accw += __shfl_xor(accw, off);
        #pragma unroll
        for (int m = 0; m < 16; ++m) accm[m] += __shfl_xor(accm[m], off);
    }
    float coeff = fmaxf(accw, 1e-8f);
    float mu[16];
    #pragma unroll
    for (int m = 0; m < 16; ++m) mu[m] = accm[m] / coeff;

    // pass 2: sigma from cached V
    float accs[16];
    #pragma unroll
    for (int m = 0; m < 16; ++m) accs[m] = 0.f;
    #pragma unroll
    for (int it = 0; it < NIT; ++it) {
        #pragma unroll
        for (int m = 0; m < 16; ++m) {
            float d = Vc[it][m] - mu[m];
            accs[m] = fmaf(wc[it], d*d, accs[m]);
        }
    }
    for (int off = 1; off < 64; off <<= 1) {
        #pragma unroll
        for (int m = 0; m < 16; ++m) accs[m] += __shfl_xor(accs[m], off);
    }

    float lsum = 0.f, is[16];
    #pragma unroll
    for (int m = 0; m < 16; ++m) {
        float s = fmaxf(accs[m] / coeff, 1e-8f);
        lsum += logf(s);
        is[m] = 1.f / s;
    }
    float ba = beta_a[j % C], bu = beta_u[j % C];
    float ao = 1.f/(1.f + expf(-(lam * (ba - (16.f*bu + 0.5f*lsum) * coeff))));

    if (lane == 0) {
        float* mo = miu  + (size_t)(bb*NJ + j)*16;
        float* io = isig + (size_t)(bb*NJ + j)*16;
        #pragma unroll
        for (int m = 0; m < 16; ++m) { mo[m] = mu[m]; io[m] = is[m]; }
        lss[bb*NJ + j] = lsum;
        aout[bb*NJ + j] = ao;
        if (final_flag) {
            a_fin[bb*NJ + j] = ao;                         // (b*C+c)*P+p == b*NJ+j
            if (M_fin) {
                #pragma unroll
                for (int m = 0; m < 16; ++m)
                    M_fin[(size_t)(bb*16 + m)*NJ + j] = mu[m];  // faithful transpose scramble
            }
        }
    }
}

// ---------------------------------------------------------------------------
// R update: one wave per (b,i). R[b,i,:] = softmax_j(a_out[j] * logp[b,i,j])
// ---------------------------------------------------------------------------
template<int NI, int NJ, int P, int C, int KK, int SHARE, int COORD>
__global__ __launch_bounds__(64) void k_R(
    const float* __restrict__ Mp, const float* __restrict__ W,
    const float* __restrict__ miu, const float* __restrict__ isig,
    const float* __restrict__ lss, const float* __restrict__ aout,
    float* __restrict__ R)
{
    constexpr int NJL = (NJ + 63) / 64;
    __shared__ float Wl[C*16];
    __shared__ float Ml[P*16];
    int i = blockIdx.x % NI, bb = blockIdx.x / NI;
    int lane = threadIdx.x;

    const float* Wsrc = SHARE ? (W + (i/KK)*C*16) : (W + (size_t)i*C*16);
    for (int k = lane; k < C*16; k += 64) Wl[k] = Wsrc[k];
    const float* Msrc = Mp + (size_t)(bb*NI + i)*P*16;
    for (int k = lane; k < P*16; k += 64) Ml[k] = Msrc[k];
    __syncthreads();

    float sv[NJL];
    float mymax = -3.0e38f;
    #pragma unroll
    for (int k = 0; k < NJL; ++k) {
        int j = lane + k*64;
        sv[k] = -3.0e38f;
        if (j < NJ) {
            int c = j / P, p = j % P;
            float V[16];
            compute_V(Wl + c*16, Ml + p*16, V);
            if (COORD) {
                int kk = i % KK;
                V[0] += (float)(kk >> 2) * 0.25f;
                V[1] += (float)(kk & 3) * 0.25f;
            }
            const float* mo = miu  + (size_t)(bb*NJ + j)*16;
            const float* io = isig + (size_t)(bb*NJ + j)*16;
            float q = 0.f;
            #pragma unroll
            for (int m = 0; m < 16; ++m) {
                float d = V[m] - mo[m];
                q = fmaf(d*d, io[m], q);
            }
            float logp = -0.5f * (16.f*LN2PI + lss[bb*NJ + j] + q);
            sv[k] = aout[bb*NJ + j] * logp;
        }
        mymax = fmaxf(mymax, sv[k]);
    }
    for (int off = 1; off < 64; off <<= 1) mymax = fmaxf(mymax, __shfl_xor(mymax, off));
    float mysum = 0.f;
    #pragma unroll
    for (int k = 0; k < NJL; ++k) {
        int j = lane + k*64;
        if (j < NJ) { sv[k] = expf(sv[k] - mymax); mysum += sv[k]; }
    }
    for (int off = 1; off < 64; off <<= 1) mysum += __shfl_xor(mysum, off);
    float inv = 1.f / mysum;
    float* Rrow = R + (size_t)(bb*NI + i)*NJ;
    #pragma unroll
    for (int k = 0; k < NJL; ++k) {
        int j = lane + k*64;
        if (j < NJ) Rrow[j] = sv[k] * inv;
    }
}

// ---------------------------------------------------------------------------
// host
// ---------------------------------------------------------------------------
template<int NI, int NJ, int P, int C, int KK, int SHARE, int COORD>
static void run_em(hipStream_t stream,
                   const float* aP, const float* Mp, const float* W,
                   const float* ba, const float* bu,
                   float* Rb, float* miu, float* isg, float* lssb, float* ao,
                   float* a_fin, float* M_fin)
{
    for (int t = 0; t < 3; ++t) {
        float lam = (float)(0.01 * (1.0 - pow(0.95, (double)(t+1))));
        k_stats<NI,NJ,P,C,KK,SHARE,COORD><<<16*NJ, 64, 0, stream>>>(
            aP, Mp, W, Rb, ba, bu, miu, isg, lssb, ao, a_fin, M_fin,
            t, lam, (t == 2) ? 1 : 0);
        if (t < 2) {
            k_R<NI,NJ,P,C,KK,SHARE,COORD><<<16*NI, 64, 0, stream>>>(
                Mp, W, miu, isg, lssb, ao, Rb);
        }
    }
}

extern "C" void kernel_launch(void* const* d_in, const int* in_sizes, int n_in,
                              void* d_out, int out_size, void* d_ws, size_t ws_size,
                              hipStream_t stream) {
    (void)in_sizes; (void)n_in; (void)out_size; (void)ws_size;
    const float* x       = (const float*)d_in[0];
    const float* conv_w  = (const float*)d_in[1];
    const float* conv_b  = (const float*)d_in[2];
    const float* pose_w  = (const float*)d_in[3];
    const float* pose_b  = (const float*)d_in[4];
    const float* act_w   = (const float*)d_in[5];
    const float* act_b   = (const float*)d_in[6];
    const float* W2      = (const float*)d_in[7];
    const float* beta_a2 = (const float*)d_in[8];
    const float* beta_u2 = (const float*)d_in[9];
    const float* W3      = (const float*)d_in[10];
    const float* beta_a3 = (const float*)d_in[11];
    const float* beta_u3 = (const float*)d_in[12];
    const float* W4      = (const float*)d_in[13];
    const float* beta_a4 = (const float*)d_in[14];
    const float* beta_u4 = (const float*)d_in[15];

    // workspace layout (floats)
    float* ws  = (float*)d_ws;
    float* fea = ws;                    // 100352
    float* a1  = fea + 100352;          // 100352
    float* M1  = a1  + 100352;          // 1605632
    float* aP  = M1  + 1605632;         // 165888 (max)
    float* Mp  = aP  + 165888;          // 2654208 (max)
    float* Rb  = Mp  + 2654208;         // 5308416 (max)
    float* miu = Rb  + 5308416;         // 294912 (max)
    float* isg = miu + 294912;          // 294912
    float* lssb= isg + 294912;          // 18432
    float* ao  = lssb+ 18432;           // 18432
    float* a2  = ao  + 18432;           // 18432
    float* M2  = a2  + 18432;           // 294912
    float* a3  = M2  + 294912;          // 8192
    float* M3  = a3  + 8192;            // 131072

    // stem + primary caps
    k_stem<<<(16*32*196 + 255)/256, 256, 0, stream>>>(x, conv_w, conv_b, fea);
    k_primary<<<(16*544*196 + 255)/256, 256, 0, stream>>>(fea, pose_w, pose_b,
                                                          act_w, act_b, M1, a1);

    // layer 2: B=32,C=32,K=3,s=2, 14x14 -> 6x6 ; ni=288, nj=1152, P=36
    k_patch<<<(16*288*36 + 255)/256, 256, 0, stream>>>(a1, M1, aP, Mp, 32, 3, 2, 14, 14, 6, 6);
    run_em<288,1152,36,32,9,0,0>(stream, aP, Mp, W2, beta_a2, beta_u2,
                                 Rb, miu, isg, lssb, ao, a2, M2);

    // layer 3: B=32,C=32,K=3,s=1, 6x6 -> 4x4 ; ni=288, nj=512, P=16
    k_patch<<<(16*288*16 + 255)/256, 256, 0, stream>>>(a2, M2, aP, Mp, 32, 3, 1, 6, 6, 4, 4);
    run_em<288,512,16,32,9,0,0>(stream, aP, Mp, W3, beta_a3, beta_u3,
                                Rb, miu, isg, lssb, ao, a3, M3);

    // layer 4: B=32,C=5,K=4,s=1, 4x4 -> 1x1 ; ni=512, nj=5, P=1, share+coord
    k_patch<<<(16*512*1 + 255)/256, 256, 0, stream>>>(a3, M3, aP, Mp, 32, 4, 1, 4, 4, 1, 1);
    run_em<512,5,1,5,16,1,1>(stream, aP, Mp, W4, beta_a4, beta_u4,
                             Rb, miu, isg, lssb, ao, (float*)d_out, nullptr);
}